// Round 5
// baseline (390.659 us; speedup 1.0000x reference)
//
#include <hip/hip_runtime.h>
#include <cstdint>
#include <cstddef>

#define B_ 16
#define S_ 64
#define T_ 4096
#define C_ 512
#define H_ 8

// ws layout (float offsets):
#define WS_QKT     0         // [512][8]
#define WS_QB      4096      // [8]
#define WS_QH      4104      // [512]
#define WS_LG      4616      // [1024][8]  softmax denominators
#define WS_CNT     12808     // [16] int
#define WS_CSEG    12824     // [16][128] int
#define WS_CIDX    14872     // [16][128] int
#define WS_CMUL    16920     // [16][128] int
#define WS_APART   18968     // [4][16][8][4096] att partials per c-slice
#define WS_WSUM    2116120   // [1024][8][512]
#define WS_ATTNOUT 6310424   // [1024][512]
// end 6834712 floats ~= 26.1 MB

// P1: qh[r] = (Wq@x + bq)[r] / 8.  grid 16, block 256.
__global__ void k_prep1(const float* __restrict__ x, const float* __restrict__ Wq,
                        const float* __restrict__ bq, float* __restrict__ qh_g) {
  __shared__ float xs[C_];
  __shared__ float red[256];
  int tid = threadIdx.x;
  xs[tid] = x[tid];
  xs[tid + 256] = x[tid + 256];
  __syncthreads();
  int r0 = blockIdx.x * 32;
  int rl = tid >> 3, sub = tid & 7;
  int r = r0 + rl;
  const float* wr = Wq + (size_t)r * C_ + sub * 64;
  const float* xp = xs + sub * 64;
  float s = 0.f;
#pragma unroll
  for (int i = 0; i < 64; i += 4) {
    float4 w = *(const float4*)(wr + i);
    s += w.x * xp[i] + w.y * xp[i + 1] + w.z * xp[i + 2] + w.w * xp[i + 3];
  }
  red[tid] = s;
  __syncthreads();
  if (sub == 0) {
    float tot = bq[r];
#pragma unroll
    for (int i = 0; i < 8; ++i) tot += red[rl * 8 + i];
    qh_g[r] = tot * 0.125f;
  }
}

// P2: qkT[c][h] = sum_d qh[h*64+d]*Wk[h*64+d][c]; qb[h] = sum_d qh*bk.
__global__ void k_prep2(const float* __restrict__ qh_g,
                        const float* __restrict__ Wk,
                        const float* __restrict__ bk, float* __restrict__ qkT,
                        float* __restrict__ qb) {
  __shared__ float qhs[64];
  int tid = threadIdx.x;
  int h = blockIdx.x;
  if (tid < 64) qhs[tid] = qh_g[h * 64 + tid];
  __syncthreads();
  int c0 = tid, c1 = tid + 256;
  float s0 = 0.f, s1 = 0.f;
#pragma unroll 8
  for (int d = 0; d < 64; ++d) {
    const float* row = Wk + (size_t)(h * 64 + d) * C_;
    float q = qhs[d];
    s0 += q * row[c0];
    s1 += q * row[c1];
  }
  qkT[c0 * 8 + h] = s0;
  qkT[c1 * 8 + h] = s1;
  if (tid < 64) {
    float w = qhs[tid] * bk[h * 64 + tid];
#pragma unroll
    for (int off = 32; off > 0; off >>= 1) w += __shfl_down(w, off, 64);
    if (tid == 0) qb[h] = w;
  }
}

// K2: att partials. apart[cg][b][h][t] = sum_{c in slice cg} qkT[c][h]*eh[b][c][t]
// grid (32, 16), block 256: 128 t per block (2 t per lane), 4 c-slices of 128.
__global__ __launch_bounds__(256, 2) void k_att(
    const float* __restrict__ eh, const float* __restrict__ qkT,
    float* __restrict__ apart) {
  __shared__ float qks[C_ * 8];  // 16 KB
  int tid = threadIdx.x;
  int tl = tid & 63, cg = tid >> 6;
  int b = blockIdx.y;
  int t0 = blockIdx.x * 128;
#pragma unroll
  for (int i = 0; i < 16; ++i) qks[tid + i * 256] = qkT[tid + i * 256];
  __syncthreads();
  const float* ehp = eh + ((size_t)b * C_ + (size_t)cg * 128) * T_ + t0 + tl;
  float acc0[8], acc1[8];
#pragma unroll
  for (int h = 0; h < 8; ++h) { acc0[h] = 0.f; acc1[h] = 0.f; }
#pragma unroll 4
  for (int j = 0; j < 128; ++j) {
    float e0 = ehp[(size_t)j * T_];
    float e1 = ehp[(size_t)j * T_ + 64];
    const float4 q0 = *(const float4*)&qks[(cg * 128 + j) * 8];
    const float4 q1 = *(const float4*)&qks[(cg * 128 + j) * 8 + 4];
    acc0[0] += q0.x * e0; acc0[1] += q0.y * e0; acc0[2] += q0.z * e0; acc0[3] += q0.w * e0;
    acc0[4] += q1.x * e0; acc0[5] += q1.y * e0; acc0[6] += q1.z * e0; acc0[7] += q1.w * e0;
    acc1[0] += q0.x * e1; acc1[1] += q0.y * e1; acc1[2] += q0.z * e1; acc1[3] += q0.w * e1;
    acc1[4] += q1.x * e1; acc1[5] += q1.y * e1; acc1[6] += q1.z * e1; acc1[7] += q1.w * e1;
  }
  float* ap = apart + (((size_t)cg * 16 + b) * 8) * T_ + t0 + tl;
#pragma unroll
  for (int h = 0; h < 8; ++h) {
    ap[(size_t)h * T_] = acc0[h];
    ap[(size_t)h * T_ + 64] = acc1[h];
  }
}

// K4: build chunk map (chunks of 128 t, interior boundaries 128-aligned
// relative to cbase = start&~31). grid 16, block 64.
__global__ void k_map(const int* __restrict__ starts,
                      const int* __restrict__ ends, int* __restrict__ cnt,
                      int* __restrict__ cseg, int* __restrict__ cidx,
                      int* __restrict__ cmul) {
  int b = blockIdx.x;
  int s = threadIdx.x;
  int st = starts[b * 64 + s], en = ends[b * 64 + s];
  int cbase = st & ~31;
  int nch = (en - cbase + 127) >> 7;
  int x = nch;
#pragma unroll
  for (int off = 1; off < 64; off <<= 1) {
    int y = __shfl_up(x, off, 64);
    if (s >= off) x += y;
  }
  int pre = x - nch;
  for (int k = 0; k < nch; ++k) {
    cseg[b * 128 + pre + k] = s;
    cidx[b * 128 + pre + k] = k;
    cmul[b * 128 + pre + k] = (nch > 1) ? 1 : 0;
  }
  if (s == 63) cnt[b] = x;
}

// K5: per chunk: e = exp(qb + sum_cg apart), l += sum(e) (atomic),
// wsum_u[n][h][c] += e[h][t]*eh[b][c][t].
// Thread owns rows c0=tid, c1=tid+256; bursts of 32 t (full 128B lines).
__global__ __launch_bounds__(256, 2) void k_wsum(
    const float* __restrict__ eh, const float* __restrict__ apart,
    const float* __restrict__ qb, const int* __restrict__ starts,
    const int* __restrict__ ends, const int* __restrict__ cnt,
    const int* __restrict__ cseg, const int* __restrict__ cidx,
    const int* __restrict__ cmul, float* __restrict__ wsum,
    float* __restrict__ l_g) {
  __shared__ float pl[8 * 132];  // [h][t-base], stride 132 (b128-aligned)
  int b = blockIdx.y;
  int i = blockIdx.x;
  if (i >= cnt[b]) return;
  int tid = threadIdx.x;
  int s = cseg[b * 128 + i];
  int k = cidx[b * 128 + i];
  int mul = cmul[b * 128 + i];
  int n = b * 64 + s;
  int st = starts[n], en = ends[n];
  int cbase = st & ~31;
  int t_lo = cbase + k * 128;
  if (st > t_lo) t_lo = st;
  int t_hi = cbase + (k + 1) * 128;
  if (en < t_hi) t_hi = en;
  int base = t_lo & ~31;
  int span = t_hi - base;           // <= 128 always
  int jpad = (span + 31) & ~31;     // 32..128; base+jpad <= T

  // stage e into pl (zero outside [t_lo, t_hi)); 8 h x 128 t
#pragma unroll
  for (int r = 0; r < 4; ++r) {
    int idx = tid + r * 256;
    int h = idx >> 7, tt = idx & 127;
    int t = base + tt;
    float pv = 0.f;
    if (t >= t_lo && t < t_hi) {
      float a = qb[h];
      size_t o = ((size_t)b * 8 + h) * T_ + t;
      a += apart[o];
      a += apart[o + (size_t)128 * T_];   // cg stride = 16*8*4096
      a += apart[o + (size_t)256 * T_];
      a += apart[o + (size_t)384 * T_];
      pv = __expf(a);
    }
    pl[h * 132 + tt] = pv;
  }
  __syncthreads();

  // softmax denominator partial -> atomicAdd
  if (tid < 64) {
    int h = tid >> 3, k8 = tid & 7;
    float ls = 0.f;
#pragma unroll
    for (int q = 0; q < 16; ++q) ls += pl[h * 132 + k8 * 16 + q];
    ls += __shfl_down(ls, 4, 8);
    ls += __shfl_down(ls, 2, 8);
    ls += __shfl_down(ls, 1, 8);
    if (k8 == 0) atomicAdd(&l_g[n * 8 + h], ls);
  }

  float acc0[8], acc1[8];
#pragma unroll
  for (int h = 0; h < 8; ++h) { acc0[h] = 0.f; acc1[h] = 0.f; }
  const float* e0p = eh + ((size_t)b * C_ + tid) * T_ + base;
  const float* e1p = e0p + (size_t)256 * T_;
  int nb = jpad >> 5;
  for (int jb = 0; jb < nb; ++jb) {
    int jo = jb * 32;
    float4 e0f[8], e1f[8];
#pragma unroll
    for (int q = 0; q < 8; ++q) e0f[q] = *(const float4*)(e0p + jo + q * 4);
#pragma unroll
    for (int q = 0; q < 8; ++q) e1f[q] = *(const float4*)(e1p + jo + q * 4);
#pragma unroll
    for (int t4 = 0; t4 < 8; ++t4) {
#pragma unroll
      for (int h = 0; h < 8; ++h) {
        const float4 p = *(const float4*)&pl[h * 132 + jo + t4 * 4];
        acc0[h] += p.x * e0f[t4].x + p.y * e0f[t4].y + p.z * e0f[t4].z +
                   p.w * e0f[t4].w;
        acc1[h] += p.x * e1f[t4].x + p.y * e1f[t4].y + p.z * e1f[t4].z +
                   p.w * e1f[t4].w;
      }
    }
  }
  float* wp = wsum + (size_t)n * (H_ * C_);
  if (!mul) {
#pragma unroll
    for (int h = 0; h < 8; ++h) {
      wp[h * C_ + tid] = acc0[h];
      wp[h * C_ + 256 + tid] = acc1[h];
    }
  } else {
#pragma unroll
    for (int h = 0; h < 8; ++h) {
      atomicAdd(&wp[h * C_ + tid], acc0[h]);
      atomicAdd(&wp[h * C_ + 256 + tid], acc1[h]);
    }
  }
}

// K6/K7: C[n][y*64+j] = (sum_k A[n*aRow + y*aColPerY + k]*Bm[(y*64+j)*512+k])
//        * (l_g ? 1/l_g[n*8+y] : 1) + bias[y*64+j].  32x64 tile.
__global__ __launch_bounds__(256, 4) void k_gemm(
    const float* __restrict__ A, long aRow, long aColPerY,
    const float* __restrict__ Bm, const float* __restrict__ bias,
    const float* __restrict__ l_g, float* __restrict__ Cc) {
  __shared__ float As[32 * 36];
  __shared__ float Bs[64 * 36];
  int tid = threadIdx.x;
  int n0 = blockIdx.x * 32;
  int y = blockIdx.y;
  const float* Abase = A + (size_t)n0 * aRow + (size_t)y * aColPerY;
  const float* Bbase = Bm + (size_t)(y * 64) * C_;
  int tx = tid & 15, ty = tid >> 4;
  float acc[2][4];
#pragma unroll
  for (int a = 0; a < 2; ++a)
#pragma unroll
    for (int bb = 0; bb < 4; ++bb) acc[a][bb] = 0.f;
  for (int k0 = 0; k0 < 512; k0 += 32) {
#pragma unroll
    for (int i = 0; i < 4; ++i) {
      int idx = tid + i * 256;
      int r = idx >> 5, cc = idx & 31;
      As[r * 36 + cc] = Abase[(size_t)r * aRow + k0 + cc];
    }
#pragma unroll
    for (int i = 0; i < 8; ++i) {
      int idx = tid + i * 256;
      int r = idx >> 5, cc = idx & 31;
      Bs[r * 36 + cc] = Bbase[(size_t)r * C_ + k0 + cc];
    }
    __syncthreads();
#pragma unroll
    for (int k = 0; k < 32; k += 4) {
      const float4 a0 = *(const float4*)&As[(ty * 2 + 0) * 36 + k];
      const float4 a1 = *(const float4*)&As[(ty * 2 + 1) * 36 + k];
#pragma unroll
      for (int bb = 0; bb < 4; ++bb) {
        const float4 bv = *(const float4*)&Bs[(tx * 4 + bb) * 36 + k];
        acc[0][bb] += a0.x * bv.x + a0.y * bv.y + a0.z * bv.z + a0.w * bv.w;
        acc[1][bb] += a1.x * bv.x + a1.y * bv.y + a1.z * bv.z + a1.w * bv.w;
      }
    }
    __syncthreads();
  }
#pragma unroll
  for (int a = 0; a < 2; ++a) {
    int nn = n0 + ty * 2 + a;
    float sc = l_g ? (1.0f / l_g[nn * 8 + y]) : 1.0f;
    float4 o;
    o.x = acc[a][0] * sc + bias[y * 64 + tx * 4 + 0];
    o.y = acc[a][1] * sc + bias[y * 64 + tx * 4 + 1];
    o.z = acc[a][2] * sc + bias[y * 64 + tx * 4 + 2];
    o.w = acc[a][3] * sc + bias[y * 64 + tx * 4 + 3];
    *(float4*)&Cc[(size_t)nn * C_ + y * 64 + tx * 4] = o;
  }
}

extern "C" void kernel_launch(void* const* d_in, const int* in_sizes, int n_in,
                              void* d_out, int out_size, void* d_ws,
                              size_t ws_size, hipStream_t stream) {
  const float* x = (const float*)d_in[0];
  const float* eh = (const float*)d_in[1];
  const int* shot_starts = (const int*)d_in[2];
  const int* shot_ends = (const int*)d_in[3];
  const float* Wq = (const float*)d_in[4];
  const float* bq = (const float*)d_in[5];
  const float* Wk = (const float*)d_in[6];
  const float* bk = (const float*)d_in[7];
  const float* Wv = (const float*)d_in[8];
  const float* bv = (const float*)d_in[9];
  const float* Wp = (const float*)d_in[10];
  const float* bp = (const float*)d_in[11];
  float* out = (float*)d_out;

  float* ws = (float*)d_ws;
  float* qkT = ws + WS_QKT;
  float* qb = ws + WS_QB;
  float* qh = ws + WS_QH;
  float* l_g = ws + WS_LG;
  int* cnt = (int*)(ws + WS_CNT);
  int* cseg = (int*)(ws + WS_CSEG);
  int* cidx = (int*)(ws + WS_CIDX);
  int* cmul = (int*)(ws + WS_CMUL);
  float* apart = ws + WS_APART;
  float* wsum = ws + WS_WSUM;
  float* attnout = ws + WS_ATTNOUT;

  hipMemsetAsync(wsum, 0, (size_t)1024 * H_ * C_ * sizeof(float), stream);
  hipMemsetAsync(l_g, 0, (size_t)1024 * H_ * sizeof(float), stream);
  k_prep1<<<16, 256, 0, stream>>>(x, Wq, bq, qh);
  k_prep2<<<8, 256, 0, stream>>>(qh, Wk, bk, qkT, qb);
  k_att<<<dim3(T_ / 128, B_), 256, 0, stream>>>(eh, qkT, apart);
  k_map<<<B_, 64, 0, stream>>>(shot_starts, shot_ends, cnt, cseg, cidx, cmul);
  k_wsum<<<dim3(128, B_), 256, 0, stream>>>(eh, apart, qb, shot_starts,
                                            shot_ends, cnt, cseg, cidx, cmul,
                                            wsum, l_g);
  k_gemm<<<dim3(32, 8), 256, 0, stream>>>(wsum, (long)(H_ * C_), (long)C_, Wv,
                                          bv, l_g, attnout);
  k_gemm<<<dim3(32, 8), 256, 0, stream>>>(attnout, (long)C_, 0L, Wp, bp,
                                          nullptr, out);
}